// Round 1
// baseline (6355.930 us; speedup 1.0000x reference)
//
#include <hip/hip_runtime.h>

// SharedResidualQuantizer: 8-step residual VQ, N=32768 rows, K=8192 codes, d=64.
// Exact argmin via fp32 screen + certified margin + fp64 refine of ambiguous rows.
//
// ws layout (bytes):
//   resid : [0,        8388608)   N*64 f32 (starts as x_code)
//   agg   : [8388608, 16777216)   N*64 f32
//   csqD  : [16777216, 17301504)  8*8192 f64
//   csqF  : [17301504, 17563648)  8*8192 f32
//   codes : [17563648, 17694720)  N int32
//   flags : [17694720, 17956864)  8*8192 int32 (per-depth flag lists)
//   acc   : [17956864, +24)       3 f64: [0]=commit, [1]=dn depth0, [2]=dn depth7
//   fcnt  : [+24, +56)            8 int32 flag counters

#define OFF_RES   0
#define OFF_AGG   8388608
#define OFF_CSQD  16777216
#define OFF_CSQF  17301504
#define OFF_CODES 17563648
#define OFF_FLAG  17694720
#define OFF_ACC   17956864

#define QSMEM_FLOATS (64*128 + 64*68 + 128 + 64)
#define QSMEM_BYTES  (QSMEM_FLOATS * 4)

// ---------------- transpose x (B,C,H,W)->(N,64) and init resid/agg ----------------
__global__ __launch_bounds__(256) void srq_transpose_init(
    const float* __restrict__ x, float* __restrict__ resid, float* __restrict__ agg)
{
  __shared__ float tile[64][65];
  const int b   = blockIdx.x >> 4;
  const int hw0 = (blockIdx.x & 15) << 6;
  const int t = threadIdx.x;
#pragma unroll
  for (int i = 0; i < 16; ++i) {
    int e = i * 256 + t;
    int c = e >> 6, hw = e & 63;
    tile[c][hw] = x[(size_t)b * 65536 + (size_t)c * 1024 + hw0 + hw];
  }
  __syncthreads();
#pragma unroll
  for (int i = 0; i < 16; ++i) {
    int e = i * 256 + t;
    int hw = e >> 6, c = e & 63;
    size_t o = ((size_t)(b * 1024 + hw0 + hw) << 6) + c;
    float v = tile[c][hw];
    resid[o] = v;
    agg[o]   = 0.f;
  }
}

// ---------------- ||c||^2 for all (depth,k) ----------------
__global__ __launch_bounds__(256) void srq_csq(
    const float* __restrict__ cb, double* __restrict__ csqD, float* __restrict__ csqF)
{
  int id = blockIdx.x * 256 + threadIdx.x;   // 65536
  const float* p = cb + ((size_t)id << 6);
  double s = 0.0;
#pragma unroll 8
  for (int d = 0; d < 64; ++d) { double v = (double)p[d]; s = fma(v, v, s); }
  csqD[id] = s;
  csqF[id] = (float)s;
}

// ---------------- fp32 screen: per-row argmin with certified gap ----------------
template <int NEED_DN>
__global__ __launch_bounds__(256) void srq_screen(
    const float* __restrict__ cbG, const float* __restrict__ csqF,
    const float* __restrict__ resid, int* __restrict__ codes,
    int* __restrict__ flagList, int* __restrict__ flagCnt,
    double* __restrict__ dnAcc)
{
  extern __shared__ float smem[];
  float* cbT  = smem;                 // [64][128] d-major
  float* resL = smem + 64 * 128;      // [64][68]
  float* csqL = resL + 64 * 68;       // [128]
  float* rsqL = csqL + 128;           // [64]
  // post-compute aliases over cbT:
  float* redV1 = smem;                // [64][16]
  float* redV2 = smem + 1024;         // [64][16]
  int*   redI  = (int*)(smem + 2048); // [64][16]
  __shared__ double dnW[4];

  const int t = threadIdx.x;
  const int row0 = blockIdx.x << 6;   // 64 rows per block
  const int kg = t & 15;              // 16 k-groups (of 8 = 4+4 split)
  const int rg = t >> 4;              // 16 row-groups (of 4)
  const int rbase = rg << 2;

  // stage residual rows
#pragma unroll
  for (int i = 0; i < 16; ++i) {
    int e = i * 256 + t;
    int r = e >> 6, d = e & 63;
    resL[r * 68 + d] = resid[((size_t)(row0 + r) << 6) + d];
  }
  __syncthreads();
  if (NEED_DN && t < 64) {
    float s = 0.f;
#pragma unroll 8
    for (int d = 0; d < 64; ++d) { float v = resL[t * 68 + d]; s = fmaf(v, v, s); }
    rsqL[t] = s;
  }
  __syncthreads();

  float rsqv[4];
  if (NEED_DN) {
#pragma unroll
    for (int i = 0; i < 4; ++i) rsqv[i] = rsqL[rbase + i];
  }

  float m1[4], m2[4];
  int   i1[4];
#pragma unroll
  for (int i = 0; i < 4; ++i) { m1[i] = 1e30f; m2[i] = 1e30f; i1[i] = 0; }
  double dn = 0.0;

  for (int tile = 0; tile < 64; ++tile) {
    const int k0 = tile << 7;
    __syncthreads();
    // stage cb tile transposed: cbT[d][k], k=0..127
#pragma unroll
    for (int j = 0; j < 8; ++j) {
      int idx = j * 256 + t;
      int k = idx & 127, dq = idx >> 7;
      float4 v = *reinterpret_cast<const float4*>(cbG + ((size_t)(k0 + k) << 6) + (dq << 2));
      cbT[(dq * 4 + 0) * 128 + k] = v.x;
      cbT[(dq * 4 + 1) * 128 + k] = v.y;
      cbT[(dq * 4 + 2) * 128 + k] = v.z;
      cbT[(dq * 4 + 3) * 128 + k] = v.w;
    }
    if (t < 128) csqL[t] = csqF[k0 + t];
    __syncthreads();

    float accA[4][4], accB[4][4];
#pragma unroll
    for (int i = 0; i < 4; ++i)
#pragma unroll
      for (int j = 0; j < 4; ++j) { accA[i][j] = 0.f; accB[i][j] = 0.f; }

    for (int d0 = 0; d0 < 64; d0 += 4) {
      float4 rr[4];
#pragma unroll
      for (int i = 0; i < 4; ++i)
        rr[i] = *reinterpret_cast<const float4*>(&resL[(rbase + i) * 68 + d0]);
#pragma unroll
      for (int dd = 0; dd < 4; ++dd) {
        float4 ca = *reinterpret_cast<const float4*>(&cbT[(d0 + dd) * 128 + (kg << 2)]);
        float4 cc = *reinterpret_cast<const float4*>(&cbT[(d0 + dd) * 128 + 64 + (kg << 2)]);
#pragma unroll
        for (int i = 0; i < 4; ++i) {
          float rv = (&rr[i].x)[dd];
          accA[i][0] = fmaf(rv, ca.x, accA[i][0]);
          accA[i][1] = fmaf(rv, ca.y, accA[i][1]);
          accA[i][2] = fmaf(rv, ca.z, accA[i][2]);
          accA[i][3] = fmaf(rv, ca.w, accA[i][3]);
          accB[i][0] = fmaf(rv, cc.x, accB[i][0]);
          accB[i][1] = fmaf(rv, cc.y, accB[i][1]);
          accB[i][2] = fmaf(rv, cc.z, accB[i][2]);
          accB[i][3] = fmaf(rv, cc.w, accB[i][3]);
        }
      }
    }

    // scores + running top-2 (ties collapse gap to 0 -> flagged -> exact refine)
#pragma unroll
    for (int j = 0; j < 4; ++j) {
      float cqA = csqL[(kg << 2) + j];
      float cqB = csqL[64 + (kg << 2) + j];
      int kA = k0 + (kg << 2) + j;
      int kB = k0 + 64 + (kg << 2) + j;
#pragma unroll
      for (int i = 0; i < 4; ++i) {
        float sA = fmaf(-2.f, accA[i][j], cqA);
        float sB = fmaf(-2.f, accB[i][j], cqB);
        if (sA < m1[i]) { m2[i] = m1[i]; m1[i] = sA; i1[i] = kA; }
        else            { m2[i] = fminf(m2[i], sA); }
        if (sB < m1[i]) { m2[i] = m1[i]; m1[i] = sB; i1[i] = kB; }
        else            { m2[i] = fminf(m2[i], sB); }
        if (NEED_DN) {
          float dA = rsqv[i] + sA;
          float dB = rsqv[i] + sB;
          dn += (double)(dA * dA);
          dn += (double)(dB * dB);
        }
      }
    }
  }

  __syncthreads();  // all compute done before aliasing cbT with reduction arrays
#pragma unroll
  for (int i = 0; i < 4; ++i) {
    redV1[(rbase + i) * 16 + kg] = m1[i];
    redV2[(rbase + i) * 16 + kg] = m2[i];
    redI [(rbase + i) * 16 + kg] = i1[i];
  }
  if (NEED_DN) {
    double dnv = dn;
#pragma unroll
    for (int o = 32; o; o >>= 1) dnv += __shfl_down(dnv, o);
    if ((t & 63) == 0) dnW[t >> 6] = dnv;
  }
  __syncthreads();

  if (t < 64) {
    float g1 = 1e30f, g2 = 1e30f;
    int gi = 0x7fffffff;
#pragma unroll
    for (int c2 = 0; c2 < 16; ++c2) {
      float v1 = redV1[t * 16 + c2];
      float v2 = redV2[t * 16 + c2];
      int ii = redI[t * 16 + c2];
      if (v1 < g1) { g2 = fminf(g1, v2); g1 = v1; gi = ii; }
      else { if (v1 == g1 && ii < gi) gi = ii; g2 = fminf(g2, v1); }
    }
    int row = row0 + t;
    codes[row] = gi;
    if (g2 - g1 < 1e-2f) {                 // certified-exact otherwise
      int pos = atomicAdd(flagCnt, 1);
      if (pos < 8192) flagList[pos] = row;
    }
  }
  if (NEED_DN && t == 0) atomicAdd(dnAcc, dnW[0] + dnW[1] + dnW[2] + dnW[3]);
}

// ---------------- fp64 exact re-scoring of ambiguous rows ----------------
__global__ __launch_bounds__(256) void srq_refine(
    const float* __restrict__ cb, const double* __restrict__ csqD,
    const float* __restrict__ resid, int* __restrict__ codes,
    const int* __restrict__ flagList, const int* __restrict__ flagCnt)
{
  __shared__ float rowv[64];
  __shared__ double vals[256];
  __shared__ int   idxs[256];
  int cnt = *flagCnt;
  if (cnt > 8192) cnt = 8192;
  for (int j = blockIdx.x; j < cnt; j += gridDim.x) {
    int row = flagList[j];
    __syncthreads();
    if (threadIdx.x < 64) rowv[threadIdx.x] = resid[((size_t)row << 6) + threadIdx.x];
    __syncthreads();
    double bv = 1e300;
    int bi = 0x7fffffff;
    for (int i = 0; i < 32; ++i) {
      int k = i * 256 + threadIdx.x;
      const float* cp = cb + ((size_t)k << 6);
      double acc2 = 0.0;
#pragma unroll 8
      for (int d = 0; d < 64; ++d) acc2 = fma((double)rowv[d], (double)cp[d], acc2);
      double s = csqD[k] - 2.0 * acc2;
      if (s < bv) { bv = s; bi = k; }   // k ascends per thread: strict < keeps first
    }
    vals[threadIdx.x] = bv;
    idxs[threadIdx.x] = bi;
    __syncthreads();
    if (threadIdx.x == 0) {
      double g = vals[0]; int gi = idxs[0];
      for (int u = 1; u < 256; ++u) {
        if (vals[u] < g || (vals[u] == g && idxs[u] < gi)) { g = vals[u]; gi = idxs[u]; }
      }
      codes[row] = gi;
    }
  }
}

// ---------------- residual/agg update, commit loss, codes output ----------------
__global__ __launch_bounds__(256) void srq_update(
    const float* __restrict__ cb, const float* __restrict__ x,
    float* __restrict__ resid, float* __restrict__ agg,
    const int* __restrict__ codes, float* __restrict__ codesF,
    double* __restrict__ commitAcc, int dep)
{
  __shared__ double w4[4];
  const int t = threadIdx.x;
  const int row = blockIdx.x * 4 + (t >> 6);
  const int c = t & 63;
  const int code = codes[row];
  float q = cb[((size_t)code << 6) + c];
  size_t ri = ((size_t)row << 6) + c;
  float r = resid[ri] - q;
  resid[ri] = r;
  float a = agg[ri] + q;
  agg[ri] = a;
  int b = row >> 10, hw = row & 1023;
  float xv = x[(size_t)b * 65536 + (size_t)c * 1024 + hw];
  float dd = xv - a;
  double cm = (double)dd * (double)dd;
#pragma unroll
  for (int o = 32; o; o >>= 1) cm += __shfl_down(cm, o);
  if ((t & 63) == 0) w4[t >> 6] = cm;
  __syncthreads();
  if (t == 0) atomicAdd(commitAcc, w4[0] + w4[1] + w4[2] + w4[3]);
  if (c == 0) codesF[(size_t)row * 8 + dep] = (float)code;
}

// ---------------- (N,64)->(B,C,H,W) straight-through write-out ----------------
__global__ __launch_bounds__(256) void srq_writeout(
    const float* __restrict__ x, const float* __restrict__ agg, float* __restrict__ out)
{
  __shared__ float tile[64][65];
  const int b   = blockIdx.x >> 4;
  const int hw0 = (blockIdx.x & 15) << 6;
  const int t = threadIdx.x;
#pragma unroll
  for (int i = 0; i < 16; ++i) {
    int e = i * 256 + t;
    int hw = e >> 6, c = e & 63;
    tile[hw][c] = agg[((size_t)(b * 1024 + hw0 + hw) << 6) + c];
  }
  __syncthreads();
#pragma unroll
  for (int i = 0; i < 16; ++i) {
    int e = i * 256 + t;
    int c = e >> 6, hw = e & 63;
    size_t o = (size_t)b * 65536 + (size_t)c * 1024 + hw0 + hw;
    float xv = x[o];
    out[o] = xv + (tile[hw][c] - xv);   // x + sg(q - x)
  }
}

__global__ void srq_finalize(const double* __restrict__ acc, float* __restrict__ outs)
{
  outs[0] = (float)(acc[0] / 16777216.0);  // commit: mean over 8*32768*64
  outs[1] = (float)(acc[2] / 32768.0);     // vqkd_d_norm  (depth 7)
  outs[2] = (float)(acc[1] / 32768.0);     // vqgan_d_norm (depth 0)
}

extern "C" void kernel_launch(void* const* d_in, const int* in_sizes, int n_in,
                              void* d_out, int out_size, void* d_ws, size_t ws_size,
                              hipStream_t stream) {
  const float* x  = (const float*)d_in[0];
  const float* cb = (const float*)d_in[1];
  char* ws = (char*)d_ws;

  float*  resid = (float*)(ws + OFF_RES);
  float*  agg   = (float*)(ws + OFF_AGG);
  double* csqD  = (double*)(ws + OFF_CSQD);
  float*  csqF  = (float*)(ws + OFF_CSQF);
  int*    codes = (int*)(ws + OFF_CODES);
  int*    flags = (int*)(ws + OFF_FLAG);
  double* acc   = (double*)(ws + OFF_ACC);
  int*    fcnt  = (int*)(ws + OFF_ACC + 24);

  float* out_vqgan = (float*)d_out;
  float* out_vqkd  = out_vqgan + 2097152;
  float* out_scal  = out_vqgan + 4194304;
  float* out_codes = out_vqgan + 4194307;

  hipMemsetAsync(ws + OFF_ACC, 0, 56, stream);
  srq_transpose_init<<<512, 256, 0, stream>>>(x, resid, agg);
  srq_csq<<<256, 256, 0, stream>>>(cb, csqD, csqF);

  for (int dep = 0; dep < 8; ++dep) {
    const float* cbd = cb + (size_t)dep * 8192 * 64;
    if (dep == 0) {
      srq_screen<1><<<512, 256, QSMEM_BYTES, stream>>>(
          cbd, csqF + dep * 8192, resid, codes, flags + dep * 8192, fcnt + dep, acc + 1);
    } else if (dep == 7) {
      srq_screen<1><<<512, 256, QSMEM_BYTES, stream>>>(
          cbd, csqF + dep * 8192, resid, codes, flags + dep * 8192, fcnt + dep, acc + 2);
    } else {
      srq_screen<0><<<512, 256, QSMEM_BYTES, stream>>>(
          cbd, csqF + dep * 8192, resid, codes, flags + dep * 8192, fcnt + dep, nullptr);
    }
    srq_refine<<<64, 256, 0, stream>>>(cbd, csqD + dep * 8192, resid, codes,
                                       flags + dep * 8192, fcnt + dep);
    srq_update<<<8192, 256, 0, stream>>>(cbd, x, resid, agg, codes, out_codes, acc, dep);
    if (dep == 0) srq_writeout<<<512, 256, 0, stream>>>(x, agg, out_vqgan);
    if (dep == 7) srq_writeout<<<512, 256, 0, stream>>>(x, agg, out_vqkd);
  }
  srq_finalize<<<1, 1, 0, stream>>>(acc, out_scal);
}

// Round 2
// 3592.830 us; speedup vs baseline: 1.7691x; 1.7691x over previous
//
#include <hip/hip_runtime.h>

// SharedResidualQuantizer: 8-step residual VQ, N=32768 rows, K=8192 codes, d=64.
// bf16 hi/lo 3-term MFMA screen + certified margin (TAU) + fp64 refine of flagged rows.
//
// ws layout (bytes):
#define OFF_RES    0u          // resid f32 N*64                     (8 MB)
#define OFF_BH     8388608u    // Bh ushort 8192*64 (per-depth)      (1 MB)
#define OFF_BL     9437184u    // Bl ushort 8192*64                  (1 MB)
#define OFF_CSQD   10485760u   // csqD f64 8*8192                    (512 KB)
#define OFF_CSQF   11010048u   // csqF f32 8*8192                    (256 KB)
#define OFF_CODES  11272192u   // codes i32 N                        (128 KB)
#define OFF_FLAG   11403264u   // flags i32 8*8192                   (256 KB)
#define OFF_RSQ    11665408u   // rsq f32 N                          (128 KB)
#define OFF_PM1    11796480u   // per-slice partials f32/i32 N*4 each (512 KB each)
#define OFF_PM2    12320768u
#define OFF_PI1    12845056u
#define OFF_PSS    13369344u
#define OFF_PSS2   13893632u
#define OFF_ACC    14417920u   // 3 f64 (commit, dn0, dn7) + 8 i32 fcnt

#define TAU 0.06f

typedef __attribute__((ext_vector_type(8))) short bf16x8;
typedef __attribute__((ext_vector_type(4))) float f32x4;

__device__ __forceinline__ unsigned short f2bf(float f) {
  unsigned u = __float_as_uint(f);
  return (unsigned short)((u + 0x7FFFu + ((u >> 16) & 1u)) >> 16);
}
__device__ __forceinline__ float bf2f(unsigned short h) {
  return __uint_as_float((unsigned)h << 16);
}
__device__ __forceinline__ f32x4 mfma16(bf16x8 a, bf16x8 b, f32x4 c) {
  return __builtin_amdgcn_mfma_f32_16x16x32_bf16(a, b, c, 0, 0, 0);
}

// ---------------- transpose x (B,C,H,W)->(N,64) into resid ----------------
__global__ __launch_bounds__(256) void srq_transpose_init(
    const float* __restrict__ x, float* __restrict__ resid)
{
  __shared__ float tile[64][65];
  const int b   = blockIdx.x >> 4;
  const int hw0 = (blockIdx.x & 15) << 6;
  const int t = threadIdx.x;
#pragma unroll
  for (int i = 0; i < 16; ++i) {
    int e = i * 256 + t;
    int c = e >> 6, hw = e & 63;
    tile[c][hw] = x[(size_t)b * 65536 + (size_t)c * 1024 + hw0 + hw];
  }
  __syncthreads();
#pragma unroll
  for (int i = 0; i < 16; ++i) {
    int e = i * 256 + t;
    int hw = e >> 6, c = e & 63;
    resid[((size_t)(b * 1024 + hw0 + hw) << 6) + c] = tile[c][hw];
  }
}

// ---------------- ||c||^2 for all (depth,k) ----------------
__global__ __launch_bounds__(256) void srq_csq(
    const float* __restrict__ cb, double* __restrict__ csqD, float* __restrict__ csqF)
{
  int id = blockIdx.x * 256 + threadIdx.x;   // 65536
  const float* p = cb + ((size_t)id << 6);
  double s = 0.0;
#pragma unroll 8
  for (int d = 0; d < 64; ++d) { double v = (double)p[d]; s = fma(v, v, s); }
  csqD[id] = s;
  csqF[id] = (float)s;
}

// ---------------- rsq of current residual ----------------
__global__ __launch_bounds__(256) void srq_rsq(
    const float* __restrict__ resid, float* __restrict__ rsq)
{
  const int t = threadIdx.x;
  const int row = blockIdx.x * 4 + (t >> 6);
  const int c = t & 63;
  float v = resid[((size_t)row << 6) + c];
  float p = v * v;
#pragma unroll
  for (int o = 32; o; o >>= 1) p += __shfl_down(p, o);
  if (c == 0) rsq[row] = p;
}

// ---------------- per-depth codebook -> bf16 hi/lo ----------------
__global__ __launch_bounds__(256) void srq_bconv(
    const float* __restrict__ cb, unsigned short* __restrict__ Bh,
    unsigned short* __restrict__ Bl)
{
  int id = blockIdx.x * 256 + threadIdx.x;   // 524288
  float v = cb[id];
  unsigned short h = f2bf(v);
  Bh[id] = h;
  Bl[id] = f2bf(v - bf2f(h));
}

// ---------------- stage one 64-code tile (hi+lo, 16 KB) to LDS ----------------
__device__ __forceinline__ void stage_tile(
    const unsigned short* __restrict__ Bh, const unsigned short* __restrict__ Bl,
    char* ldsbase, int k0, int wid, int lane)
{
#pragma unroll
  for (int q = 0; q < 4; ++q) {
    int ub = (((q << 2) + wid) << 10);       // wave-uniform dest base (1 KB chunks)
    int db = ub + lane * 16;                 // effective dest byte (for src swizzle)
    int half = db >> 13;                     // 0 = hi tile, 1 = lo tile
    int rowh = (db & 8191) >> 7;             // code row within half
    int soff = (db & 127) ^ ((rowh & 7) << 4);  // inverse-swizzled source offset
    const unsigned short* g = (half ? Bl : Bh) + (((size_t)(k0 + rowh)) << 6) + (soff >> 1);
    __builtin_amdgcn_global_load_lds(
        (const __attribute__((address_space(1))) void*)g,
        (__attribute__((address_space(3))) void*)(ldsbase + ub), 16, 0, 0);
  }
}

// ---------------- MFMA screen: per-row top-2 (+ sum s, sum s^2) ----------------
template <int NEED_DN>
__global__ __launch_bounds__(256, 2) void srq_screen_mfma(
    const unsigned short* __restrict__ Bh, const unsigned short* __restrict__ Bl,
    const float* __restrict__ csqF, const float* __restrict__ resid,
    float* __restrict__ pm1, float* __restrict__ pm2, int* __restrict__ pi1,
    float* __restrict__ pss, float* __restrict__ pss2)
{
  __shared__ char lds[32768];                // 2 bufs x (Bh 8KB + Bl 8KB)
  const int tid = threadIdx.x;
  const int lane = tid & 63;
  const int wid = tid >> 6;
  const int rg = blockIdx.x & 127;           // row group (256 rows)
  const int ks = blockIdx.x >> 7;            // k slice (2048 codes)
  const int k0g = ks << 11;
  const int wrow0 = (rg << 8) + (wid << 6);  // wave owns 64 rows
  const int lr = lane & 15;
  const int kg = lane >> 4;

  // A fragments: 64 rows x 64 d, hi/lo, converted from exact f32 residual
  bf16x8 ah[4][2], al[4][2];
#pragma unroll
  for (int rf = 0; rf < 4; ++rf)
#pragma unroll
    for (int s = 0; s < 2; ++s) {
      const float* rp = resid + (((size_t)(wrow0 + rf * 16 + lr)) << 6) + s * 32 + kg * 8;
      float4 v0 = *(const float4*)rp;
      float4 v1 = *(const float4*)(rp + 4);
      float f[8] = {v0.x, v0.y, v0.z, v0.w, v1.x, v1.y, v1.z, v1.w};
      bf16x8 h, l;
#pragma unroll
      for (int e = 0; e < 8; ++e) {
        unsigned short hh = f2bf(f[e]);
        h[e] = (short)hh;
        l[e] = (short)f2bf(f[e] - bf2f(hh));
      }
      ah[rf][s] = h;
      al[rf][s] = l;
    }

  float m1[16], m2[16];
  int i1[16];
  float sS[16], sQ[16];
#pragma unroll
  for (int j = 0; j < 16; ++j) { m1[j] = 3e38f; m2[j] = 3e38f; i1[j] = 0; sS[j] = 0.f; sQ[j] = 0.f; }

  stage_tile(Bh, Bl, lds, k0g, wid, lane);

  for (int t = 0; t < 32; ++t) {
    __syncthreads();   // compiler drains vmcnt here: staged tile t visible
    if (t < 31) stage_tile(Bh, Bl, lds + (((t + 1) & 1) << 14), k0g + ((t + 1) << 6), wid, lane);
    const char* bb = lds + ((t & 1) << 14);
    const int k0 = k0g + (t << 6);
    float cq[4];
#pragma unroll
    for (int cf = 0; cf < 4; ++cf) cq[cf] = csqF[k0 + cf * 16 + lr];
#pragma unroll
    for (int cf = 0; cf < 4; ++cf) {
      const int cl = cf * 16 + lr;           // local code (B-frag col)
      const int sw = (cl & 7) << 4;          // XOR swizzle
      const int ro = cl * 128 + kg * 16;
      bf16x8 bh0 = *(const bf16x8*)(bb + ((ro) ^ sw));
      bf16x8 bh1 = *(const bf16x8*)(bb + ((ro + 64) ^ sw));
      bf16x8 bl0 = *(const bf16x8*)(bb + 8192 + ((ro) ^ sw));
      bf16x8 bl1 = *(const bf16x8*)(bb + 8192 + ((ro + 64) ^ sw));
      const int code = k0 + cl;
#pragma unroll
      for (int rf = 0; rf < 4; ++rf) {
        f32x4 acc = {0.f, 0.f, 0.f, 0.f};
        acc = mfma16(al[rf][0], bh0, acc);   // lo.hi
        acc = mfma16(al[rf][1], bh1, acc);
        acc = mfma16(ah[rf][0], bl0, acc);   // hi.lo
        acc = mfma16(ah[rf][1], bl1, acc);
        acc = mfma16(ah[rf][0], bh0, acc);   // hi.hi
        acc = mfma16(ah[rf][1], bh1, acc);
#pragma unroll
        for (int r = 0; r < 4; ++r) {
          float s = fmaf(-2.f, acc[r], cq[cf]);
          const int j = rf * 4 + r;          // row = wrow0 + rf*16 + kg*4 + r
          bool lt = s < m1[j];
          m2[j] = __builtin_amdgcn_fmed3f(s, m1[j], m2[j]);
          m1[j] = fminf(m1[j], s);
          i1[j] = lt ? code : i1[j];
          if (NEED_DN) { sS[j] += s; sQ[j] = fmaf(s, s, sQ[j]); }
        }
      }
    }
  }

  // merge across the 16 lanes (lane^{1,2,4,8}) sharing each row
#pragma unroll
  for (int j = 0; j < 16; ++j) {
    float a1 = m1[j], a2 = m2[j];
    int ai = i1[j];
    float t1 = sS[j], t2 = sQ[j];
#pragma unroll
    for (int w = 1; w <= 8; w <<= 1) {
      float b1 = __shfl_xor(a1, w);
      float b2 = __shfl_xor(a2, w);
      int bi = __shfl_xor(ai, w);
      float nm2 = fminf(fmaxf(a1, b1), fminf(a2, b2));
      bool bet = (b1 < a1) || (b1 == a1 && bi < ai);
      a1 = fminf(a1, b1);
      ai = bet ? bi : ai;
      a2 = nm2;
      if (NEED_DN) { t1 += __shfl_xor(t1, w); t2 += __shfl_xor(t2, w); }
    }
    if (lr == 0) {
      const int row = wrow0 + (j >> 2) * 16 + kg * 4 + (j & 3);
      pm1[row * 4 + ks] = a1;
      pm2[row * 4 + ks] = a2;
      pi1[row * 4 + ks] = ai;
      if (NEED_DN) { pss[row * 4 + ks] = t1; pss2[row * 4 + ks] = t2; }
    }
  }
}

// ---------------- merge 4 k-slices: codes, flags, d_norm ----------------
template <int NEED_DN>
__global__ __launch_bounds__(256) void srq_merge(
    const float* __restrict__ pm1, const float* __restrict__ pm2,
    const int* __restrict__ pi1, const float* __restrict__ pss,
    const float* __restrict__ pss2, const float* __restrict__ rsq,
    int* __restrict__ codes, int* __restrict__ flagList, int* __restrict__ flagCnt,
    double* __restrict__ dnAcc)
{
  __shared__ double w4[4];
  const int row = blockIdx.x * 256 + threadIdx.x;
  float m1 = pm1[row * 4], m2 = pm2[row * 4];
  int i1 = pi1[row * 4];
  float S = 0.f, Q = 0.f;
  if (NEED_DN) { S = pss[row * 4]; Q = pss2[row * 4]; }
#pragma unroll
  for (int k = 1; k < 4; ++k) {
    float b1 = pm1[row * 4 + k], b2 = pm2[row * 4 + k];
    int bi = pi1[row * 4 + k];
    m2 = fminf(fmaxf(m1, b1), fminf(m2, b2));
    if (b1 < m1) { m1 = b1; i1 = bi; }       // slices ascend: ties keep earlier
    if (NEED_DN) { S += pss[row * 4 + k]; Q += pss2[row * 4 + k]; }
  }
  codes[row] = i1;
  if (m2 - m1 < TAU) {
    int p = atomicAdd(flagCnt, 1);
    if (p < 8192) flagList[p] = row;
  }
  if (NEED_DN) {
    float rs = rsq[row];
    double dn = 8192.0 * (double)rs * (double)rs + 2.0 * (double)rs * (double)S + (double)Q;
#pragma unroll
    for (int o = 32; o; o >>= 1) dn += __shfl_down(dn, o);
    if ((threadIdx.x & 63) == 0) w4[threadIdx.x >> 6] = dn;
    __syncthreads();
    if (threadIdx.x == 0) atomicAdd(dnAcc, w4[0] + w4[1] + w4[2] + w4[3]);
  }
}

// ---------------- fp64 exact re-scoring of flagged rows ----------------
__global__ __launch_bounds__(256) void srq_refine(
    const float* __restrict__ cb, const double* __restrict__ csqD,
    const float* __restrict__ resid, int* __restrict__ codes,
    const int* __restrict__ flagList, const int* __restrict__ flagCnt)
{
  __shared__ float rowv[64];
  __shared__ double vals[256];
  __shared__ int   idxs[256];
  int cnt = *flagCnt;
  if (cnt > 8192) cnt = 8192;
  for (int j = blockIdx.x; j < cnt; j += gridDim.x) {
    int row = flagList[j];
    __syncthreads();
    if (threadIdx.x < 64) rowv[threadIdx.x] = resid[((size_t)row << 6) + threadIdx.x];
    __syncthreads();
    double bv = 1e300;
    int bi = 0x7fffffff;
    for (int i = 0; i < 32; ++i) {
      int k = i * 256 + threadIdx.x;
      const float* cp = cb + ((size_t)k << 6);
      double acc2 = 0.0;
#pragma unroll 8
      for (int d = 0; d < 64; ++d) acc2 = fma((double)rowv[d], (double)cp[d], acc2);
      double s = csqD[k] - 2.0 * acc2;
      if (s < bv) { bv = s; bi = k; }        // k ascends per thread: strict < keeps first
    }
    vals[threadIdx.x] = bv;
    idxs[threadIdx.x] = bi;
    __syncthreads();
    if (threadIdx.x == 0) {
      double g = vals[0]; int gi = idxs[0];
      for (int u = 1; u < 256; ++u) {
        if (vals[u] < g || (vals[u] == g && idxs[u] < gi)) { g = vals[u]; gi = idxs[u]; }
      }
      codes[row] = gi;
    }
  }
}

// ---------------- residual update, rsq, commit, codes output ----------------
__global__ __launch_bounds__(256) void srq_update(
    const float* __restrict__ cb, float* __restrict__ resid,
    const int* __restrict__ codes, float* __restrict__ codesF,
    float* __restrict__ rsq, double* __restrict__ commitAcc, int dep)
{
  __shared__ double w4[4];
  const int t = threadIdx.x;
  const int row = blockIdx.x * 4 + (t >> 6);
  const int c = t & 63;
  const int code = codes[row];
  float q = cb[((size_t)code << 6) + c];
  size_t ri = ((size_t)row << 6) + c;
  float r = resid[ri] - q;
  resid[ri] = r;
  float p = r * r;
#pragma unroll
  for (int o = 32; o; o >>= 1) p += __shfl_down(p, o);
  if (c == 0) { rsq[row] = p; w4[t >> 6] = (double)p; }
  __syncthreads();
  if (t == 0) atomicAdd(commitAcc, w4[0] + w4[1] + w4[2] + w4[3]);
  if (c == 0) codesF[(size_t)row * 8 + dep] = (float)code;
}

// ---------------- (N,64)->(B,C,H,W) straight-through write-out ----------------
__global__ __launch_bounds__(256) void srq_writeout(
    const float* __restrict__ x, const float* __restrict__ resid, float* __restrict__ out)
{
  __shared__ float tile[64][65];
  const int b   = blockIdx.x >> 4;
  const int hw0 = (blockIdx.x & 15) << 6;
  const int t = threadIdx.x;
#pragma unroll
  for (int i = 0; i < 16; ++i) {
    int e = i * 256 + t;
    int hw = e >> 6, c = e & 63;
    tile[hw][c] = resid[((size_t)(b * 1024 + hw0 + hw) << 6) + c];
  }
  __syncthreads();
#pragma unroll
  for (int i = 0; i < 16; ++i) {
    int e = i * 256 + t;
    int c = e >> 6, hw = e & 63;
    size_t o = (size_t)b * 65536 + (size_t)c * 1024 + hw0 + hw;
    out[o] = x[o] - tile[hw][c];   // x + sg(q - x), q = x_code - resid
  }
}

__global__ void srq_finalize(const double* __restrict__ acc, float* __restrict__ outs)
{
  outs[0] = (float)(acc[0] / 16777216.0);  // commit: mean over 8*32768*64
  outs[1] = (float)(acc[2] / 32768.0);     // vqkd_d_norm  (depth 7)
  outs[2] = (float)(acc[1] / 32768.0);     // vqgan_d_norm (depth 0)
}

extern "C" void kernel_launch(void* const* d_in, const int* in_sizes, int n_in,
                              void* d_out, int out_size, void* d_ws, size_t ws_size,
                              hipStream_t stream) {
  const float* x  = (const float*)d_in[0];
  const float* cb = (const float*)d_in[1];
  char* ws = (char*)d_ws;

  float*  resid = (float*)(ws + OFF_RES);
  unsigned short* Bh = (unsigned short*)(ws + OFF_BH);
  unsigned short* Bl = (unsigned short*)(ws + OFF_BL);
  double* csqD  = (double*)(ws + OFF_CSQD);
  float*  csqF  = (float*)(ws + OFF_CSQF);
  int*    codes = (int*)(ws + OFF_CODES);
  int*    flags = (int*)(ws + OFF_FLAG);
  float*  rsq   = (float*)(ws + OFF_RSQ);
  float*  pm1   = (float*)(ws + OFF_PM1);
  float*  pm2   = (float*)(ws + OFF_PM2);
  int*    pi1   = (int*)(ws + OFF_PI1);
  float*  pss   = (float*)(ws + OFF_PSS);
  float*  pss2  = (float*)(ws + OFF_PSS2);
  double* acc   = (double*)(ws + OFF_ACC);
  int*    fcnt  = (int*)(ws + OFF_ACC + 24);

  float* out_vqgan = (float*)d_out;
  float* out_vqkd  = out_vqgan + 2097152;
  float* out_scal  = out_vqgan + 4194304;
  float* out_codes = out_vqgan + 4194307;

  hipMemsetAsync(ws + OFF_ACC, 0, 56, stream);
  srq_transpose_init<<<512, 256, 0, stream>>>(x, resid);
  srq_csq<<<256, 256, 0, stream>>>(cb, csqD, csqF);
  srq_rsq<<<8192, 256, 0, stream>>>(resid, rsq);

  for (int dep = 0; dep < 8; ++dep) {
    const float* cbd = cb + (size_t)dep * 524288;
    srq_bconv<<<2048, 256, 0, stream>>>(cbd, Bh, Bl);
    const float* cf = csqF + dep * 8192;
    if (dep == 0 || dep == 7) {
      srq_screen_mfma<1><<<512, 256, 0, stream>>>(Bh, Bl, cf, resid, pm1, pm2, pi1, pss, pss2);
      srq_merge<1><<<128, 256, 0, stream>>>(pm1, pm2, pi1, pss, pss2, rsq, codes,
          flags + dep * 8192, fcnt + dep, acc + (dep == 0 ? 1 : 2));
    } else {
      srq_screen_mfma<0><<<512, 256, 0, stream>>>(Bh, Bl, cf, resid, pm1, pm2, pi1, pss, pss2);
      srq_merge<0><<<128, 256, 0, stream>>>(pm1, pm2, pi1, pss, pss2, rsq, codes,
          flags + dep * 8192, fcnt + dep, nullptr);
    }
    srq_refine<<<256, 256, 0, stream>>>(cbd, csqD + dep * 8192, resid, codes,
                                        flags + dep * 8192, fcnt + dep);
    srq_update<<<8192, 256, 0, stream>>>(cbd, resid, codes, out_codes, rsq, acc, dep);
    if (dep == 0) srq_writeout<<<512, 256, 0, stream>>>(x, resid, out_vqgan);
    if (dep == 7) srq_writeout<<<512, 256, 0, stream>>>(x, resid, out_vqkd);
  }
  srq_finalize<<<1, 1, 0, stream>>>(acc, out_scal);
}

// Round 3
// 2897.872 us; speedup vs baseline: 2.1933x; 1.2398x over previous
//
#include <hip/hip_runtime.h>

// SharedResidualQuantizer: 8-step residual VQ, N=32768 rows, K=8192 codes, d=64.
// f16 hi/scaled-lo MFMA screen (exact hi*hi products) + certified margin TAU
// + fp64 refine of flagged rows (refine also performs those rows' update).
//
// ws layout (bytes):
#define OFF_RES    0u          // resid f32 N*64                     (8 MB)
#define OFF_BH     8388608u    // Bh f16 8192*64 (per-depth)         (1 MB)
#define OFF_BL     9437184u    // Bl f16 (scaled 2^11)               (1 MB)
#define OFF_CSQD   10485760u   // csqD f64 8*8192                    (512 KB)
#define OFF_CSQF   11010048u   // csqF f32 8*8192                    (256 KB)
#define OFF_CODES  11272192u   // codes i32 N                        (128 KB)
#define OFF_RSQ    11403264u   // rsq f32 N                          (128 KB)
#define OFF_PM1    11534336u   // per-slice partials, N*4 each       (512 KB each)
#define OFF_PM2    12058624u
#define OFF_PI1    12582912u
#define OFF_PSS    13107200u
#define OFF_PSS2   13631488u
#define OFF_FLAG   14155776u   // flag list i32 N (reused per depth) (128 KB)
#define OFF_ACC    14286848u   // 3 f64 (commit, dn0, dn7) + 8 i32 fcnt

#define TAU 3.0e-3f

typedef __attribute__((ext_vector_type(8))) _Float16 f16x8;
typedef __attribute__((ext_vector_type(4))) float f32x4;

__device__ __forceinline__ f32x4 mfma16(f16x8 a, f16x8 b, f32x4 c) {
  return __builtin_amdgcn_mfma_f32_16x16x32_f16(a, b, c, 0, 0, 0);
}

// ---------------- transpose x (B,C,H,W)->(N,64) into resid ----------------
__global__ __launch_bounds__(256) void srq_transpose_init(
    const float* __restrict__ x, float* __restrict__ resid)
{
  __shared__ float tile[64][65];
  const int b   = blockIdx.x >> 4;
  const int hw0 = (blockIdx.x & 15) << 6;
  const int t = threadIdx.x;
#pragma unroll
  for (int i = 0; i < 16; ++i) {
    int e = i * 256 + t;
    int c = e >> 6, hw = e & 63;
    tile[c][hw] = x[(size_t)b * 65536 + (size_t)c * 1024 + hw0 + hw];
  }
  __syncthreads();
#pragma unroll
  for (int i = 0; i < 16; ++i) {
    int e = i * 256 + t;
    int hw = e >> 6, c = e & 63;
    resid[((size_t)(b * 1024 + hw0 + hw) << 6) + c] = tile[c][hw];
  }
}

// ---------------- ||c||^2 for all (depth,k) ----------------
__global__ __launch_bounds__(256) void srq_csq(
    const float* __restrict__ cb, double* __restrict__ csqD, float* __restrict__ csqF)
{
  int id = blockIdx.x * 256 + threadIdx.x;   // 65536
  const float* p = cb + ((size_t)id << 6);
  double s = 0.0;
#pragma unroll 8
  for (int d = 0; d < 64; ++d) { double v = (double)p[d]; s = fma(v, v, s); }
  csqD[id] = s;
  csqF[id] = (float)s;
}

// ---------------- rsq of initial residual ----------------
__global__ __launch_bounds__(256) void srq_rsq(
    const float* __restrict__ resid, float* __restrict__ rsq)
{
  const int t = threadIdx.x;
  const int row = blockIdx.x * 4 + (t >> 6);
  const int c = t & 63;
  float v = resid[((size_t)row << 6) + c];
  float p = v * v;
#pragma unroll
  for (int o = 32; o; o >>= 1) p += __shfl_down(p, o);
  if (c == 0) rsq[row] = p;
}

// ---------------- per-depth codebook -> f16 hi + scaled lo ----------------
__global__ __launch_bounds__(256) void srq_bconv(
    const float* __restrict__ cb, _Float16* __restrict__ Bh, _Float16* __restrict__ Bl)
{
  int id = blockIdx.x * 256 + threadIdx.x;   // 524288
  float v = cb[id];
  _Float16 h = (_Float16)v;
  Bh[id] = h;
  Bl[id] = (_Float16)((v - (float)h) * 2048.f);
}

// ---------------- stage one 64-code tile (hi+lo, 16 KB) to LDS ----------------
__device__ __forceinline__ void stage_tile(
    const _Float16* __restrict__ Bh, const _Float16* __restrict__ Bl,
    char* ldsbase, int k0, int wid, int lane)
{
#pragma unroll
  for (int q = 0; q < 4; ++q) {
    int ub = (((q << 2) + wid) << 10);       // wave-uniform dest base (1 KB chunks)
    int db = ub + lane * 16;                 // effective dest byte (for src swizzle)
    int half = db >> 13;                     // 0 = hi tile, 1 = lo tile
    int rowh = (db & 8191) >> 7;             // code row within half
    int soff = (db & 127) ^ ((rowh & 7) << 4);  // inverse-swizzled source offset
    const _Float16* g = (half ? Bl : Bh) + (((size_t)(k0 + rowh)) << 6) + (soff >> 1);
    __builtin_amdgcn_global_load_lds(
        (const __attribute__((address_space(1))) void*)g,
        (__attribute__((address_space(3))) void*)(ldsbase + ub), 16, 0, 0);
  }
}

// ---------------- MFMA screen: per-row top-2 (+ sum s, sum s^2) ----------------
template <int NEED_DN>
__global__ __launch_bounds__(256, 2) void srq_screen_mfma(
    const _Float16* __restrict__ Bh, const _Float16* __restrict__ Bl,
    const float* __restrict__ csqF, const float* __restrict__ resid,
    float* __restrict__ pm1, float* __restrict__ pm2, int* __restrict__ pi1,
    float* __restrict__ pss, float* __restrict__ pss2)
{
  __shared__ char lds[32768];                // 2 bufs x (Bh 8KB + Bl 8KB)
  const int tid = threadIdx.x;
  const int lane = tid & 63;
  const int wid = tid >> 6;
  const int rg = blockIdx.x & 127;           // row group (256 rows)
  const int ks = blockIdx.x >> 7;            // k slice (2048 codes)
  const int k0g = ks << 11;
  const int wrow0 = (rg << 8) + (wid << 6);  // wave owns 64 rows
  const int lr = lane & 15;
  const int kg = lane >> 4;

  // A fragments: 64 rows x 64 d, f16 hi + scaled lo, from exact f32 residual
  f16x8 ah[4][2], al[4][2];
#pragma unroll
  for (int rf = 0; rf < 4; ++rf)
#pragma unroll
    for (int s = 0; s < 2; ++s) {
      const float* rp = resid + (((size_t)(wrow0 + rf * 16 + lr)) << 6) + s * 32 + kg * 8;
      float4 v0 = *(const float4*)rp;
      float4 v1 = *(const float4*)(rp + 4);
      float f[8] = {v0.x, v0.y, v0.z, v0.w, v1.x, v1.y, v1.z, v1.w};
      f16x8 h, l;
#pragma unroll
      for (int e = 0; e < 8; ++e) {
        _Float16 hh = (_Float16)f[e];
        h[e] = hh;
        l[e] = (_Float16)((f[e] - (float)hh) * 2048.f);
      }
      ah[rf][s] = h;
      al[rf][s] = l;
    }

  float m1[16], m2[16];
  int i1[16];
  float sS[16], sQ[16];
#pragma unroll
  for (int j = 0; j < 16; ++j) { m1[j] = 3e38f; m2[j] = 3e38f; i1[j] = 0; sS[j] = 0.f; sQ[j] = 0.f; }

  stage_tile(Bh, Bl, lds, k0g, wid, lane);

  for (int t = 0; t < 32; ++t) {
    __syncthreads();   // compiler drains vmcnt here: staged tile t visible
    if (t < 31) stage_tile(Bh, Bl, lds + (((t + 1) & 1) << 14), k0g + ((t + 1) << 6), wid, lane);
    const char* bb = lds + ((t & 1) << 14);
    const int k0 = k0g + (t << 6);
    float cq[4];
#pragma unroll
    for (int cf = 0; cf < 4; ++cf) cq[cf] = csqF[k0 + cf * 16 + lr];
#pragma unroll
    for (int cf = 0; cf < 4; ++cf) {
      const int cl = cf * 16 + lr;           // local code (B-frag col)
      const int sw = (cl & 7) << 4;          // XOR swizzle
      const int ro = cl * 128 + kg * 16;
      f16x8 bh0 = *(const f16x8*)(bb + ((ro) ^ sw));
      f16x8 bh1 = *(const f16x8*)(bb + ((ro + 64) ^ sw));
      f16x8 bl0 = *(const f16x8*)(bb + 8192 + ((ro) ^ sw));
      f16x8 bl1 = *(const f16x8*)(bb + 8192 + ((ro + 64) ^ sw));
      const int code = k0 + cl;
#pragma unroll
      for (int rf = 0; rf < 4; ++rf) {
        f32x4 a1 = {0.f, 0.f, 0.f, 0.f};     // hi*hi (exact products)
        f32x4 a2 = {0.f, 0.f, 0.f, 0.f};     // cross terms at 2^11 scale
        a1 = mfma16(ah[rf][0], bh0, a1);
        a1 = mfma16(ah[rf][1], bh1, a1);
        a2 = mfma16(ah[rf][0], bl0, a2);
        a2 = mfma16(ah[rf][1], bl1, a2);
        a2 = mfma16(al[rf][0], bh0, a2);
        a2 = mfma16(al[rf][1], bh1, a2);
#pragma unroll
        for (int r = 0; r < 4; ++r) {
          // s = cq - 2*a1 - 2^-10*a2
          float s = fmaf(-2.f, a1[r], fmaf(-0.0009765625f, a2[r], cq[cf]));
          const int j = rf * 4 + r;          // row = wrow0 + rf*16 + kg*4 + r
          bool lt = s < m1[j];
          m2[j] = __builtin_amdgcn_fmed3f(s, m1[j], m2[j]);
          m1[j] = fminf(m1[j], s);
          i1[j] = lt ? code : i1[j];
          if (NEED_DN) { sS[j] += s; sQ[j] = fmaf(s, s, sQ[j]); }
        }
      }
    }
  }

  // merge across the 16 lanes (lane^{1,2,4,8}) sharing each row
#pragma unroll
  for (int j = 0; j < 16; ++j) {
    float a1 = m1[j], a2 = m2[j];
    int ai = i1[j];
    float t1 = sS[j], t2 = sQ[j];
#pragma unroll
    for (int w = 1; w <= 8; w <<= 1) {
      float b1 = __shfl_xor(a1, w);
      float b2 = __shfl_xor(a2, w);
      int bi = __shfl_xor(ai, w);
      float nm2 = fminf(fmaxf(a1, b1), fminf(a2, b2));
      bool bet = (b1 < a1) || (b1 == a1 && bi < ai);
      a1 = fminf(a1, b1);
      ai = bet ? bi : ai;
      a2 = nm2;
      if (NEED_DN) { t1 += __shfl_xor(t1, w); t2 += __shfl_xor(t2, w); }
    }
    if (lr == 0) {
      const int row = wrow0 + (j >> 2) * 16 + kg * 4 + (j & 3);
      pm1[row * 4 + ks] = a1;
      pm2[row * 4 + ks] = a2;
      pi1[row * 4 + ks] = ai;
      if (NEED_DN) { pss[row * 4 + ks] = t1; pss2[row * 4 + ks] = t2; }
    }
  }
}

// ------- fused merge(4 slices) + update(resid/rsq/commit/codes), flag ambiguous -------
template <int NEED_DN>
__global__ __launch_bounds__(256) void srq_merge_update(
    const float* __restrict__ pm1, const float* __restrict__ pm2,
    const int* __restrict__ pi1, const float* __restrict__ pss,
    const float* __restrict__ pss2, const float* __restrict__ cb,
    float* __restrict__ resid, float* __restrict__ rsq,
    int* __restrict__ codes, float* __restrict__ codesF,
    int* __restrict__ flagList, int* __restrict__ flagCnt,
    double* __restrict__ commitAcc, double* __restrict__ dnAcc, int dep)
{
  __shared__ double w4[4];
  __shared__ double dnW[4];
  const int t = threadIdx.x;
  const int team = t >> 6;
  const int c = t & 63;
  const int row = blockIdx.x * 4 + team;

  // all 64 lanes of a team redundantly merge (broadcast loads)
  float m1 = pm1[row * 4], m2 = pm2[row * 4];
  int i1 = pi1[row * 4];
  float S = 0.f, Q = 0.f;
  if (NEED_DN) { S = pss[row * 4]; Q = pss2[row * 4]; }
#pragma unroll
  for (int k = 1; k < 4; ++k) {
    float b1 = pm1[row * 4 + k], b2 = pm2[row * 4 + k];
    int bi = pi1[row * 4 + k];
    m2 = fminf(fmaxf(m1, b1), fminf(m2, b2));
    if (b1 < m1) { m1 = b1; i1 = bi; }       // slices ascend: ties keep earlier
    if (NEED_DN) { S += pss[row * 4 + k]; Q += pss2[row * 4 + k]; }
  }
  const int code = i1;
  const bool ok = (m2 - m1) >= TAU;

  if (NEED_DN && c == 0) {
    float rs = rsq[row];   // pre-update rsq
    dnW[team] = 8192.0 * (double)rs * (double)rs + 2.0 * (double)rs * (double)S + (double)Q;
  }

  float p = 0.f;
  if (ok) {
    float q = cb[((size_t)code << 6) + c];
    size_t ri = ((size_t)row << 6) + c;
    float r = resid[ri] - q;
    resid[ri] = r;
    p = r * r;
  }
#pragma unroll
  for (int o = 32; o; o >>= 1) p += __shfl_down(p, o);
  if (c == 0) {
    codes[row] = code;                       // refine overwrites flagged rows
    codesF[(size_t)row * 8 + dep] = (float)code;
    w4[team] = (double)p;
    if (ok) {
      rsq[row] = p;
    } else {
      int pos = atomicAdd(flagCnt, 1);
      flagList[pos] = row;
    }
  }
  __syncthreads();
  if (t == 0) atomicAdd(commitAcc, w4[0] + w4[1] + w4[2] + w4[3]);
  if (NEED_DN && t == 1) atomicAdd(dnAcc, dnW[0] + dnW[1] + dnW[2] + dnW[3]);
}

// ------- fp64 exact re-scoring of flagged rows + their deferred update -------
__global__ __launch_bounds__(256) void srq_refine(
    const float* __restrict__ cb, const double* __restrict__ csqD,
    float* __restrict__ resid, int* __restrict__ codes,
    const int* __restrict__ flagList, const int* __restrict__ flagCnt,
    float* __restrict__ rsq, float* __restrict__ codesF,
    double* __restrict__ commitAcc, int dep)
{
  __shared__ float rowv[64];
  __shared__ double vals[256];
  __shared__ int   idxs[256];
  __shared__ int   sbest;
  int cnt = *flagCnt;
  for (int j = blockIdx.x; j < cnt; j += gridDim.x) {
    int row = flagList[j];
    __syncthreads();
    if (threadIdx.x < 64) rowv[threadIdx.x] = resid[((size_t)row << 6) + threadIdx.x];
    __syncthreads();
    double bv = 1e300;
    int bi = 0x7fffffff;
    for (int i = 0; i < 32; ++i) {
      int k = i * 256 + threadIdx.x;
      const float* cp = cb + ((size_t)k << 6);
      double a0 = 0.0, a1 = 0.0, a2 = 0.0, a3 = 0.0;
#pragma unroll
      for (int d = 0; d < 64; d += 4) {
        a0 = fma((double)rowv[d    ], (double)cp[d    ], a0);
        a1 = fma((double)rowv[d + 1], (double)cp[d + 1], a1);
        a2 = fma((double)rowv[d + 2], (double)cp[d + 2], a2);
        a3 = fma((double)rowv[d + 3], (double)cp[d + 3], a3);
      }
      double s = csqD[k] - 2.0 * ((a0 + a1) + (a2 + a3));
      if (s < bv) { bv = s; bi = k; }        // k ascends per thread: strict < keeps first
    }
    vals[threadIdx.x] = bv;
    idxs[threadIdx.x] = bi;
    __syncthreads();
    if (threadIdx.x == 0) {
      double g = vals[0]; int gi = idxs[0];
      for (int u = 1; u < 256; ++u) {
        if (vals[u] < g || (vals[u] == g && idxs[u] < gi)) { g = vals[u]; gi = idxs[u]; }
      }
      codes[row] = gi;
      codesF[(size_t)row * 8 + dep] = (float)gi;
      sbest = gi;
    }
    __syncthreads();
    if (threadIdx.x < 64) {
      int code = sbest;
      float q = cb[((size_t)code << 6) + threadIdx.x];
      float r = rowv[threadIdx.x] - q;
      resid[((size_t)row << 6) + threadIdx.x] = r;
      float p = r * r;
#pragma unroll
      for (int o = 32; o; o >>= 1) p += __shfl_down(p, o);
      if (threadIdx.x == 0) {
        rsq[row] = p;
        atomicAdd(commitAcc, (double)p);
      }
    }
  }
}

// ---------------- (N,64)->(B,C,H,W) straight-through write-out ----------------
__global__ __launch_bounds__(256) void srq_writeout(
    const float* __restrict__ x, const float* __restrict__ resid, float* __restrict__ out)
{
  __shared__ float tile[64][65];
  const int b   = blockIdx.x >> 4;
  const int hw0 = (blockIdx.x & 15) << 6;
  const int t = threadIdx.x;
#pragma unroll
  for (int i = 0; i < 16; ++i) {
    int e = i * 256 + t;
    int hw = e >> 6, c = e & 63;
    tile[hw][c] = resid[((size_t)(b * 1024 + hw0 + hw) << 6) + c];
  }
  __syncthreads();
#pragma unroll
  for (int i = 0; i < 16; ++i) {
    int e = i * 256 + t;
    int c = e >> 6, hw = e & 63;
    size_t o = (size_t)b * 65536 + (size_t)c * 1024 + hw0 + hw;
    out[o] = x[o] - tile[hw][c];   // x + sg(q - x), q = x_code - resid
  }
}

__global__ void srq_finalize(const double* __restrict__ acc, float* __restrict__ outs)
{
  outs[0] = (float)(acc[0] / 16777216.0);  // commit: mean over 8*32768*64
  outs[1] = (float)(acc[2] / 32768.0);     // vqkd_d_norm  (depth 7)
  outs[2] = (float)(acc[1] / 32768.0);     // vqgan_d_norm (depth 0)
}

extern "C" void kernel_launch(void* const* d_in, const int* in_sizes, int n_in,
                              void* d_out, int out_size, void* d_ws, size_t ws_size,
                              hipStream_t stream) {
  const float* x  = (const float*)d_in[0];
  const float* cb = (const float*)d_in[1];
  char* ws = (char*)d_ws;

  float*  resid = (float*)(ws + OFF_RES);
  _Float16* Bh  = (_Float16*)(ws + OFF_BH);
  _Float16* Bl  = (_Float16*)(ws + OFF_BL);
  double* csqD  = (double*)(ws + OFF_CSQD);
  float*  csqF  = (float*)(ws + OFF_CSQF);
  int*    codes = (int*)(ws + OFF_CODES);
  float*  rsq   = (float*)(ws + OFF_RSQ);
  float*  pm1   = (float*)(ws + OFF_PM1);
  float*  pm2   = (float*)(ws + OFF_PM2);
  int*    pi1   = (int*)(ws + OFF_PI1);
  float*  pss   = (float*)(ws + OFF_PSS);
  float*  pss2  = (float*)(ws + OFF_PSS2);
  int*    flags = (int*)(ws + OFF_FLAG);
  double* acc   = (double*)(ws + OFF_ACC);
  int*    fcnt  = (int*)(ws + OFF_ACC + 24);

  float* out_vqgan = (float*)d_out;
  float* out_vqkd  = out_vqgan + 2097152;
  float* out_scal  = out_vqgan + 4194304;
  float* out_codes = out_vqgan + 4194307;

  hipMemsetAsync(ws + OFF_ACC, 0, 56, stream);
  srq_transpose_init<<<512, 256, 0, stream>>>(x, resid);
  srq_csq<<<256, 256, 0, stream>>>(cb, csqD, csqF);
  srq_rsq<<<8192, 256, 0, stream>>>(resid, rsq);

  for (int dep = 0; dep < 8; ++dep) {
    const float* cbd = cb + (size_t)dep * 524288;
    srq_bconv<<<2048, 256, 0, stream>>>(cbd, Bh, Bl);
    const float* cf = csqF + dep * 8192;
    if (dep == 0 || dep == 7) {
      double* dn = acc + (dep == 0 ? 1 : 2);
      srq_screen_mfma<1><<<512, 256, 0, stream>>>(Bh, Bl, cf, resid, pm1, pm2, pi1, pss, pss2);
      srq_merge_update<1><<<8192, 256, 0, stream>>>(pm1, pm2, pi1, pss, pss2, cbd,
          resid, rsq, codes, out_codes, flags, fcnt + dep, acc, dn, dep);
    } else {
      srq_screen_mfma<0><<<512, 256, 0, stream>>>(Bh, Bl, cf, resid, pm1, pm2, pi1, pss, pss2);
      srq_merge_update<0><<<8192, 256, 0, stream>>>(pm1, pm2, pi1, pss, pss2, cbd,
          resid, rsq, codes, out_codes, flags, fcnt + dep, acc, nullptr, dep);
    }
    srq_refine<<<128, 256, 0, stream>>>(cbd, csqD + dep * 8192, resid, codes,
                                        flags, fcnt + dep, rsq, out_codes, acc, dep);
    if (dep == 0) srq_writeout<<<512, 256, 0, stream>>>(x, resid, out_vqgan);
    if (dep == 7) srq_writeout<<<512, 256, 0, stream>>>(x, resid, out_vqkd);
  }
  srq_finalize<<<1, 1, 0, stream>>>(acc, out_scal);
}